// Round 9
// baseline (261.236 us; speedup 1.0000x reference)
//
#include <hip/hip_runtime.h>
#include <hip/hip_bf16.h>

typedef __attribute__((ext_vector_type(8))) short bf16x8;
typedef __attribute__((ext_vector_type(4))) float f32x4;
typedef __attribute__((ext_vector_type(16))) float f32x16;

namespace {

__device__ __forceinline__ unsigned short f2bf(float f) {
  unsigned int x;
  __builtin_memcpy(&x, &f, 4);
  x += 0x7fff + ((x >> 16) & 1);  // round-to-nearest-even
  return (unsigned short)(x >> 16);
}
__device__ __forceinline__ unsigned int pack2(float a, float b) {
  return (unsigned int)f2bf(a) | ((unsigned int)f2bf(b) << 16);
}

// ============================ wprep kernel ============================
// R2-proven weight reorder branch: wAll bf16 [1024 x 256];
// rows g*32+r for g<24 = wqkv row (g%3)*256+(g/3)*32+r; g>=24 = wout rows.
__global__ __launch_bounds__(256) void wprep(const float* __restrict__ wqkv,
                                             const float* __restrict__ wout,
                                             unsigned short* __restrict__ wAll) {
  const int g = blockIdx.x;           // 0..31
  const int tid = threadIdx.x;
  const int row_l = tid >> 3;         // 0..31
  const int seg = tid & 7;            // 8 segs x 32 elems
  const float* src;
  int srow;
  if (g < 24) { src = wqkv; srow = (g % 3) * 256 + (g / 3) * 32 + row_l; }
  else        { src = wout; srow = (g - 24) * 32 + row_l; }
  const float* s = src + (size_t)srow * 256 + seg * 32;
  unsigned short* d = wAll + ((size_t)(g * 32 + row_l)) * 256 + seg * 32;
#pragma unroll
  for (int u = 0; u < 8; ++u) {
    const float4 v = *(const float4*)(s + u * 4);
    uint2 p;
    p.x = pack2(v.x, v.y);
    p.y = pack2(v.z, v.w);
    *(uint2*)(d + u * 4) = p;
  }
}

// ============================ main kernel (L2-weight) ============================
// v10: ZERO main-loop barriers. R8 evidence chain: barrier count (R7),
// occupancy (R3/R4), MFMA chain ILP (R8) all null -> the stall is the
// lockstep stage->vmcnt(0)-drain->compute cycle itself. Weights are only
// 512KB bf16 (L2/L1-resident, shared by all blocks), so MFMA B-frags are
// read DIRECTLY from global wAll (b128 L2 hits; 16KB/tile fits L1 for
// cross-wave reuse). No WB dbuf, no pw prefetch, no staging barriers:
// 8 waves free-run over 24 tiles + softmax on wave-private site buffers.
// Phase X, softmax, sitebufs (vt s20), fbuf/store path: R8-identical.
constexpr int kPanelStride = 72;            // x-panel row stride (16B-aligned)
constexpr int kPanel = 16 * 16 * kPanelStride;  // 18432 shorts
constexpr int kSiteL = 1920;                // q640(s40)|k640(s40,P s24)|vt640(s20)
constexpr int kSmemL = kPanel + 8 * kSiteL; // 33792 shorts = 67584 B (<=160KB OK, R7 proved >64KB)
static_assert(512 * 17 * 4 <= kPanel * 2, "fbuf fits in panel region");

__global__ __launch_bounds__(512, 1) void attn_l2w(
    const float* __restrict__ x,              // (4,16,256,32,32) fp32
    const float* __restrict__ rel,            // (8,16,16) fp32
    const unsigned short* __restrict__ wAll,  // (1024,256) bf16 reordered
    const float* __restrict__ bqkv,           // (768,) fp32
    const float* __restrict__ bout,           // (256,) fp32
    float* __restrict__ out) {                // (4,16,256,32,32) fp32
  __shared__ __align__(16) unsigned short smem[kSmemL];
  const int tid = threadIdx.x;
  const int lane = tid & 63;
  const int wave = tid >> 6;
  const int quad = lane >> 4;
  const int lrow = lane & 15;
  const int half = lane >> 5;
  const int n32 = lane & 31;
  const int b = blockIdx.x >> 6;
  const int hw0 = (blockIdx.x & 63) * 16;

  // ---- phase X: stage x into bf16 panel, extract A-frags (R8-identical) ----
  // ax semantics: A[m=n32][k=ks*16+half*8+j] =
  //   x_bf16[b][t=lrow][c=k][hw = hw0 + 2*wave + (n32>>4)]
  bf16x8 ax[16];
  {
    unsigned short* panel = smem;
    const int sloc = wave * 2 + (n32 >> 4);
#pragma unroll
    for (int cc4 = 0; cc4 < 4; ++cc4) {  // full unroll: ax statically indexed
      const int c0 = cc4 * 64;
      __syncthreads();  // panel free (prev chunk's readers done)
#pragma unroll
      for (int u = 0; u < 8; ++u) {
        const int idx = u * 512 + tid;
        const int row = idx >> 2;  // t*64 + cl
        const int q = idx & 3;     // which 4-hw chunk
        const int t = row >> 6;
        const int cl = row & 63;
        const float4 v = *(const float4*)(
            x + (((size_t)(b * 16 + t) * 256 + c0 + cl) << 10) + hw0 + q * 4);
        unsigned short* pr = panel + (t * 16 + q * 4) * kPanelStride + cl;
        pr[0] = f2bf(v.x);
        pr[kPanelStride] = f2bf(v.y);
        pr[2 * kPanelStride] = f2bf(v.z);
        pr[3 * kPanelStride] = f2bf(v.w);
      }
      __syncthreads();  // panel ready
#pragma unroll
      for (int kk = 0; kk < 4; ++kk)
        ax[cc4 * 4 + kk] = *(const bf16x8*)(
            panel + (lrow * 16 + sloc) * kPanelStride + kk * 16 + half * 8);
    }
  }

  unsigned short* qb = smem + kPanel + wave * kSiteL;
  unsigned short* kb = qb + 640;
  unsigned short* vt = qb + 1280;  // stride 20, [d][j]

  const f32x4 zero4 = {0.f, 0.f, 0.f, 0.f};
  const float scale = 0.17677669529663687f;  // 32^-0.5
  bf16x8 ao[2][8];

  // 16-kstep 32x32x16 MFMA, B-frags direct from global wAll (L2/L1 hit).
  // Two independent 8-chains (even/odd ks) for pipe ILP.
  auto qkv_tile = [&](int g, float bias) -> f32x16 {
    f32x16 accA, accB;
#pragma unroll
    for (int i = 0; i < 16; ++i) { accA[i] = bias; accB[i] = 0.f; }
    const unsigned short* br = wAll + (((size_t)(g * 32 + n32)) << 8) + half * 8;
#pragma unroll
    for (int kp = 0; kp < 8; ++kp) {
      const bf16x8 bfa = *(const bf16x8*)(br + (2 * kp) * 16);
      const bf16x8 bfb = *(const bf16x8*)(br + (2 * kp + 1) * 16);
      accA = __builtin_amdgcn_mfma_f32_32x32x16_bf16(ax[2 * kp], bfa, accA, 0, 0, 0);
      accB = __builtin_amdgcn_mfma_f32_32x32x16_bf16(ax[2 * kp + 1], bfb, accB, 0, 0, 0);
    }
#pragma unroll
    for (int i = 0; i < 16; ++i) accA[i] += accB[i];
    return accA;
  };

  // one head, h literal at each call site; NO barriers (sitebufs wave-private)
  auto head_body = [&](int h) {
    const f32x16 qacc = qkv_tile(h * 3 + 0, bqkv[h * 32 + n32]);
    const f32x16 kacc = qkv_tile(h * 3 + 1, bqkv[256 + h * 32 + n32]);
    const f32x16 vacc = qkv_tile(h * 3 + 2, bqkv[512 + h * 32 + n32]);
    float rl[4];
#pragma unroll
    for (int r = 0; r < 4; ++r) rl[r] = rel[h * 256 + (quad * 4 + r) * 16 + lrow];

#pragma unroll
    for (int s = 0; s < 2; ++s) {
      // C/D 32x32: reg=8s+rr -> row=16s+t, t=(rr&3)+8*(rr>>2)+4*half, col=n32
#pragma unroll
      for (int rr = 0; rr < 8; ++rr) {
        const int t = (rr & 3) + 8 * (rr >> 2) + 4 * half;
        qb[t * 40 + n32] = f2bf(qacc[8 * s + rr]);
        kb[t * 40 + n32] = f2bf(kacc[8 * s + rr]);
      }
#pragma unroll
      for (int rp = 0; rp < 4; ++rp) {  // vT[d][j] stride 20, paired t (b32)
        const int rr = rp * 2;
        const int t = (rr & 3) + 8 * (rr >> 2) + 4 * half;
        *(unsigned int*)&vt[n32 * 20 + t] =
            pack2(vacc[8 * s + rr], vacc[8 * s + rr + 1]);
      }
      // sim (16x16x32): A=q[m=t][k=d], B[k=d][n=j]=k[j][d]
      const bf16x8 qf = *(const bf16x8*)(qb + lrow * 40 + quad * 8);
      const bf16x8 kf = *(const bf16x8*)(kb + lrow * 40 + quad * 8);
      const f32x4 sim = __builtin_amdgcn_mfma_f32_16x16x32_bf16(qf, kf, zero4, 0, 0, 0);
      float p[4], inv[4];
#pragma unroll
      for (int r = 0; r < 4; ++r) {
        const float v = sim[r] * scale + rl[r];
        float m = v;
        for (int off = 8; off; off >>= 1) m = fmaxf(m, __shfl_xor(m, off));
        const float e = __expf(v - m);
        float sum = e;
        for (int off = 8; off; off >>= 1) sum += __shfl_xor(sum, off);
        p[r] = e;
        inv[r] = 1.0f / sum;
      }
      unsigned short* pb = kb;  // P overlays k (dead), stride 24
#pragma unroll
      for (int r = 0; r < 4; ++r) pb[(quad * 4 + r) * 24 + lrow] = f2bf(p[r]);
      bf16x8 pf, vf0, vf1;
      if (quad < 2) {
        pf = *(const bf16x8*)(pb + lrow * 24 + quad * 8);
        vf0 = *(const bf16x8*)(vt + lrow * 20 + quad * 8);
        vf1 = *(const bf16x8*)(vt + (16 + lrow) * 20 + quad * 8);
      } else {
#pragma unroll
        for (int j = 0; j < 8; ++j) { pf[j] = 0; vf0[j] = 0; vf1[j] = 0; }
      }
      const f32x4 o0 = __builtin_amdgcn_mfma_f32_16x16x32_bf16(pf, vf0, zero4, 0, 0, 0);
      const f32x4 o1 = __builtin_amdgcn_mfma_f32_16x16x32_bf16(pf, vf1, zero4, 0, 0, 0);
#pragma unroll
      for (int r = 0; r < 4; ++r) {  // O bounce into qb (dead) -> A-layout
        const int t = quad * 4 + r;
        qb[t * 40 + lrow] = f2bf(o0[r] * inv[r]);
        qb[t * 40 + 16 + lrow] = f2bf(o1[r] * inv[r]);
      }
      ao[s][h] = *(const bf16x8*)(qb + lrow * 40 + quad * 8);
    }
  };

  head_body(0);
  head_body(1);
  head_body(2);
  head_body(3);
  head_body(4);
  head_body(5);
  head_body(6);
  head_body(7);

  // ---- epilogue: y = O @ wout^T + bout; wf direct from wAll rows 768+
  // (R2-proven pattern); fbuf bounce + 64-B coalesced stores (R8 path). ----
  __syncthreads();  // all waves done with panel/sitebufs; fbuf overlays smem
  float* fbuf = (float*)smem;  // 512 lines x 17 floats
  float* ob = out + ((size_t)b << 22);
#pragma unroll 1
  for (int cc = 0; cc < 8; ++cc) {
#pragma unroll
    for (int sub = 0; sub < 2; ++sub) {
      const int c = cc * 32 + sub * 16 + lrow;
      const float bias = bout[c];
      f32x4 y0 = {bias, bias, bias, bias};
      f32x4 y1 = {bias, bias, bias, bias};
#pragma unroll
      for (int ks = 0; ks < 8; ++ks) {
        const bf16x8 wf =
            *(const bf16x8*)(wAll + (size_t)(768 + c) * 256 + ks * 32 + quad * 8);
        y0 = __builtin_amdgcn_mfma_f32_16x16x32_bf16(ao[0][ks], wf, y0, 0, 0, 0);
        y1 = __builtin_amdgcn_mfma_f32_16x16x32_bf16(ao[1][ks], wf, y1, 0, 0, 0);
      }
#pragma unroll
      for (int r = 0; r < 4; ++r) {
        const int t = quad * 4 + r;
        const int L = (t * 32 + sub * 16 + lrow) * 17 + wave * 2;
        fbuf[L] = y0[r];
        fbuf[L + 1] = y1[r];
      }
    }
    __syncthreads();
    {
      const int t = tid >> 5, cl = tid & 31;
      float v[16];
#pragma unroll
      for (int i = 0; i < 16; ++i) v[i] = fbuf[tid * 17 + i];
      float* dst = ob + ((size_t)(t * 256 + cc * 32 + cl)) * 1024 + hw0;
#pragma unroll
      for (int u = 0; u < 4; ++u) {
        float4 q;
        q.x = v[u * 4]; q.y = v[u * 4 + 1]; q.z = v[u * 4 + 2]; q.w = v[u * 4 + 3];
        *(float4*)(dst + u * 4) = q;
      }
    }
    __syncthreads();
  }
}

// ============================ fallback (R8, passed, no workspace) ============================
constexpr int kWBStride = 264;                 // 256 + 8 pad (elems)
constexpr int kWBTile = 32 * kWBStride;        // 8448 elems
constexpr int kWB = 2 * kWBTile;               // 16896 elems
constexpr int kSite = 1920;                    // q640(s40)|k640(s40,P s24)|vt640(s20)
constexpr int kSmem = kWB + 8 * kSite;         // 32256 elems = 64512 B
constexpr int kWTileOff = 17408;               // shorts; after fbuf (512*17 floats)
static_assert(kSmem * 2 <= 160 * 1024, "LDS budget");

__global__ __launch_bounds__(512, 1) void attn_fused(
    const float* __restrict__ x, const float* __restrict__ rel,
    const float* __restrict__ wqkv, const float* __restrict__ bqkv,
    const float* __restrict__ wout, const float* __restrict__ bout,
    float* __restrict__ out) {
  __shared__ __align__(16) unsigned short smem[kSmem];
  const int tid = threadIdx.x;
  const int lane = tid & 63;
  const int wave = tid >> 6;
  const int quad = lane >> 4;
  const int lrow = lane & 15;
  const int half = lane >> 5;
  const int n32 = lane & 31;
  const int b = blockIdx.x >> 6;
  const int hw0 = (blockIdx.x & 63) * 16;

  const int wrow = tid >> 4;
  const int wcol = (tid & 15) * 16;
  float4 pw[4];
  {
    const float* sp = wqkv + (size_t)wrow * 256 + wcol;
#pragma unroll
    for (int u = 0; u < 4; ++u) pw[u] = *(const float4*)(sp + u * 4);
  }

  bf16x8 ax[16];
  {
    unsigned short* panel = smem;
    const int sloc = wave * 2 + (n32 >> 4);
#pragma unroll
    for (int cc4 = 0; cc4 < 4; ++cc4) {
      const int c0 = cc4 * 64;
      __syncthreads();
#pragma unroll
      for (int u = 0; u < 8; ++u) {
        const int idx = u * 512 + tid;
        const int row = idx >> 2;
        const int q = idx & 3;
        const int t = row >> 6;
        const int cl = row & 63;
        const float4 v = *(const float4*)(
            x + (((size_t)(b * 16 + t) * 256 + c0 + cl) << 10) + hw0 + q * 4);
        unsigned short* pr = panel + (t * 16 + q * 4) * kPanelStride + cl;
        pr[0] = f2bf(v.x);
        pr[kPanelStride] = f2bf(v.y);
        pr[2 * kPanelStride] = f2bf(v.z);
        pr[3 * kPanelStride] = f2bf(v.w);
      }
      __syncthreads();
#pragma unroll
      for (int kk = 0; kk < 4; ++kk)
        ax[cc4 * 4 + kk] = *(const bf16x8*)(
            panel + (lrow * 16 + sloc) * kPanelStride + kk * 16 + half * 8);
    }
  }

  unsigned short* qb = smem + kWB + wave * kSite;
  unsigned short* kb = qb + 640;
  unsigned short* vt = qb + 1280;

  const f32x4 zero4 = {0.f, 0.f, 0.f, 0.f};
  const float scale = 0.17677669529663687f;
  bf16x8 ao[2][8];

  auto qkv_tile = [&](int g, float bias) -> f32x16 {
    __syncthreads();
    unsigned short* WBc = smem + (g & 1) * kWBTile;
    {
      unsigned short* dst = WBc + wrow * kWBStride + wcol;
      uint4 a, bq;
      a.x = pack2(pw[0].x, pw[0].y);
      a.y = pack2(pw[0].z, pw[0].w);
      a.z = pack2(pw[1].x, pw[1].y);
      a.w = pack2(pw[1].z, pw[1].w);
      bq.x = pack2(pw[2].x, pw[2].y);
      bq.y = pack2(pw[2].z, pw[2].w);
      bq.z = pack2(pw[3].x, pw[3].y);
      bq.w = pack2(pw[3].z, pw[3].w);
      *(uint4*)dst = a;
      *(uint4*)(dst + 8) = bq;
    }
    {
      const int gn = g + 1;
      const int rowbase = (gn % 3) * 256 + (gn / 3) * 32;
      const float* sp = wqkv + (size_t)(rowbase + wrow) * 256 + wcol;
#pragma unroll
      for (int u = 0; u < 4; ++u) pw[u] = *(const float4*)(sp + u * 4);
    }
    __syncthreads();
    f32x16 accA, accB;
#pragma unroll
    for (int i = 0; i < 16; ++i) { accA[i] = bias; accB[i] = 0.f; }
    const unsigned short* br = WBc + n32 * kWBStride + half * 8;
#pragma unroll
    for (int kp = 0; kp < 8; ++kp) {
      const bf16x8 bfa = *(const bf16x8*)(br + (2 * kp) * 16);
      const bf16x8 bfb = *(const bf16x8*)(br + (2 * kp + 1) * 16);
      accA = __builtin_amdgcn_mfma_f32_32x32x16_bf16(ax[2 * kp], bfa, accA, 0, 0, 0);
      accB = __builtin_amdgcn_mfma_f32_32x32x16_bf16(ax[2 * kp + 1], bfb, accB, 0, 0, 0);
    }
#pragma unroll
    for (int i = 0; i < 16; ++i) accA[i] += accB[i];
    return accA;
  };

  auto head_body = [&](int h) {
    const f32x16 qacc = qkv_tile(h * 3 + 0, bqkv[h * 32 + n32]);
    const f32x16 kacc = qkv_tile(h * 3 + 1, bqkv[256 + h * 32 + n32]);
    const f32x16 vacc = qkv_tile(h * 3 + 2, bqkv[512 + h * 32 + n32]);
    float rl[4];
#pragma unroll
    for (int r = 0; r < 4; ++r) rl[r] = rel[h * 256 + (quad * 4 + r) * 16 + lrow];

#pragma unroll
    for (int s = 0; s < 2; ++s) {
#pragma unroll
      for (int rr = 0; rr < 8; ++rr) {
        const int t = (rr & 3) + 8 * (rr >> 2) + 4 * half;
        qb[t * 40 + n32] = f2bf(qacc[8 * s + rr]);
        kb[t * 40 + n32] = f2bf(kacc[8 * s + rr]);
      }
#pragma unroll
      for (int rp = 0; rp < 4; ++rp) {
        const int rr = rp * 2;
        const int t = (rr & 3) + 8 * (rr >> 2) + 4 * half;
        *(unsigned int*)&vt[n32 * 20 + t] =
            pack2(vacc[8 * s + rr], vacc[8 * s + rr + 1]);
      }
      const bf16x8 qf = *(const bf16x8*)(qb + lrow * 40 + quad * 8);
      const bf16x8 kf = *(const bf16x8*)(kb + lrow * 40 + quad * 8);
      const f32x4 sim = __builtin_amdgcn_mfma_f32_16x16x32_bf16(qf, kf, zero4, 0, 0, 0);
      float p[4], inv[4];
#pragma unroll
      for (int r = 0; r < 4; ++r) {
        const float v = sim[r] * scale + rl[r];
        float m = v;
        for (int off = 8; off; off >>= 1) m = fmaxf(m, __shfl_xor(m, off));
        const float e = __expf(v - m);
        float sum = e;
        for (int off = 8; off; off >>= 1) sum += __shfl_xor(sum, off);
        p[r] = e;
        inv[r] = 1.0f / sum;
      }
      unsigned short* pb = kb;
#pragma unroll
      for (int r = 0; r < 4; ++r) pb[(quad * 4 + r) * 24 + lrow] = f2bf(p[r]);
      bf16x8 pf, vf0, vf1;
      if (quad < 2) {
        pf = *(const bf16x8*)(pb + lrow * 24 + quad * 8);
        vf0 = *(const bf16x8*)(vt + lrow * 20 + quad * 8);
        vf1 = *(const bf16x8*)(vt + (16 + lrow) * 20 + quad * 8);
      } else {
#pragma unroll
        for (int j = 0; j < 8; ++j) { pf[j] = 0; vf0[j] = 0; vf1[j] = 0; }
      }
      const f32x4 o0 = __builtin_amdgcn_mfma_f32_16x16x32_bf16(pf, vf0, zero4, 0, 0, 0);
      const f32x4 o1 = __builtin_amdgcn_mfma_f32_16x16x32_bf16(pf, vf1, zero4, 0, 0, 0);
#pragma unroll
      for (int r = 0; r < 4; ++r) {
        const int t = quad * 4 + r;
        qb[t * 40 + lrow] = f2bf(o0[r] * inv[r]);
        qb[t * 40 + 16 + lrow] = f2bf(o1[r] * inv[r]);
      }
      ao[s][h] = *(const bf16x8*)(qb + lrow * 40 + quad * 8);
    }
  };

  head_body(0);
  head_body(1);
  head_body(2);
  head_body(3);
  head_body(4);
  head_body(5);
  head_body(6);
  head_body(7);

  __syncthreads();
  float* fbuf = (float*)smem;
  unsigned short* wtile = smem + kWTileOff;
  float* ob = out + ((size_t)b << 22);
#pragma unroll 1
  for (int cc = 0; cc < 8; ++cc) {
    {
      const float* sp = wout + (size_t)(cc * 32 + wrow) * 256 + wcol;
      const float4 v0 = ((const float4*)sp)[0];
      const float4 v1 = ((const float4*)sp)[1];
      const float4 v2 = ((const float4*)sp)[2];
      const float4 v3 = ((const float4*)sp)[3];
      uint4 a, bq;
      a.x = pack2(v0.x, v0.y);
      a.y = pack2(v0.z, v0.w);
      a.z = pack2(v1.x, v1.y);
      a.w = pack2(v1.z, v1.w);
      bq.x = pack2(v2.x, v2.y);
      bq.y = pack2(v2.z, v2.w);
      bq.z = pack2(v3.x, v3.y);
      bq.w = pack2(v3.z, v3.w);
      unsigned short* d = wtile + wrow * kWBStride + wcol;
      *(uint4*)d = a;
      *(uint4*)(d + 8) = bq;
    }
    __syncthreads();
#pragma unroll
    for (int sub = 0; sub < 2; ++sub) {
      const int c = cc * 32 + sub * 16 + lrow;
      const float bias = bout[c];
      f32x4 y0 = {bias, bias, bias, bias};
      f32x4 y1 = {bias, bias, bias, bias};
      const unsigned short* wrow_p = wtile + (sub * 16 + lrow) * kWBStride;
#pragma unroll
      for (int ks = 0; ks < 8; ++ks) {
        const bf16x8 wf = *(const bf16x8*)(wrow_p + ks * 32 + quad * 8);
        y0 = __builtin_amdgcn_mfma_f32_16x16x32_bf16(ao[0][ks], wf, y0, 0, 0, 0);
        y1 = __builtin_amdgcn_mfma_f32_16x16x32_bf16(ao[1][ks], wf, y1, 0, 0, 0);
      }
#pragma unroll
      for (int r = 0; r < 4; ++r) {
        const int t = quad * 4 + r;
        const int L = (t * 32 + sub * 16 + lrow) * 17 + wave * 2;
        fbuf[L] = y0[r];
        fbuf[L + 1] = y1[r];
      }
    }
    __syncthreads();
    {
      const int t = tid >> 5, cl = tid & 31;
      float v[16];
#pragma unroll
      for (int i = 0; i < 16; ++i) v[i] = fbuf[tid * 17 + i];
      float* dst = ob + ((size_t)(t * 256 + cc * 32 + cl)) * 1024 + hw0;
#pragma unroll
      for (int u = 0; u < 4; ++u) {
        float4 q;
        q.x = v[u * 4]; q.y = v[u * 4 + 1]; q.z = v[u * 4 + 2]; q.w = v[u * 4 + 3];
        *(float4*)(dst + u * 4) = q;
      }
    }
    __syncthreads();
  }
}

}  // namespace

extern "C" void kernel_launch(void* const* d_in, const int* in_sizes, int n_in,
                              void* d_out, int out_size, void* d_ws, size_t ws_size,
                              hipStream_t stream) {
  const float* x = (const float*)d_in[0];
  const float* rel = (const float*)d_in[1];
  const float* wqkv = (const float*)d_in[2];
  const float* bqkv = (const float*)d_in[3];
  const float* wout = (const float*)d_in[4];
  const float* bout = (const float*)d_in[5];
  float* out = (float*)d_out;
  (void)in_sizes; (void)n_in; (void)out_size;

  constexpr size_t kWAllBytes = (size_t)1024 * 256 * sizeof(unsigned short);
  if (ws_size >= kWAllBytes) {
    unsigned short* wAll = (unsigned short*)d_ws;
    wprep<<<32, 256, 0, stream>>>(wqkv, wout, wAll);
    attn_l2w<<<256, 512, 0, stream>>>(x, rel, wAll, bqkv, bout, out);
  } else {
    attn_fused<<<256, 512, 0, stream>>>(x, rel, wqkv, bqkv, wout, bout, out);
  }
}

// Round 10
// 223.415 us; speedup vs baseline: 1.1693x; 1.1693x over previous
//
#include <hip/hip_runtime.h>
#include <hip/hip_bf16.h>

typedef __attribute__((ext_vector_type(8))) short bf16x8;
typedef __attribute__((ext_vector_type(4))) float f32x4;
typedef __attribute__((ext_vector_type(16))) float f32x16;

namespace {

__device__ __forceinline__ unsigned short f2bf(float f) {
  unsigned int x;
  __builtin_memcpy(&x, &f, 4);
  x += 0x7fff + ((x >> 16) & 1);  // round-to-nearest-even
  return (unsigned short)(x >> 16);
}
__device__ __forceinline__ unsigned int pack2(float a, float b) {
  return (unsigned int)f2bf(a) | ((unsigned int)f2bf(b) << 16);
}

// ============================ fused kernel ============================
// v11 = v7/R6 (proven best: 111us) + three LATENCY-HIDING edits only
// (structure untouched; R3/R4/R7/R8/R9 proved all structural levers null
// or negative):
//  (1) all 24 bqkv biases preloaded to regs before the head loop -- R6
//      loaded each at acc-init right after barrier2 (~500cy exposed x24).
//  (2) phase X: chunk's 8 float4 register-prefetched one chunk ahead.
//  (3) epilogue software pipeline: dbuf wtile+fbuf (LDS 103KB, still
//      1 block/CU), wout reg-prefetched one cc ahead, fully unrolled,
//      ONE barrier per cc (was 3); stores of cc-1 overlap MFMAs of cc.
constexpr int kWBStride = 264;                 // 256 + 8 pad (elems)
constexpr int kWBTile = 32 * kWBStride;        // 8448 elems
constexpr int kWB = 2 * kWBTile;               // 16896 elems
constexpr int kSite = 1824;                    // q640(s40)|k640(s40,P s24)|vt512(s16)|pad
constexpr int kSmemMain = kWB + 8 * kSite;     // 31488 shorts (main loop region)
constexpr int kPanelStride = 72;               // x-panel row stride (16B-aligned b128)
// epilogue overlay: fb0[8704 f]=17408 sh | fb1 | wt0[8448 sh] | wt1
constexpr int kFb1 = 17408;
constexpr int kWt0 = 34816;
constexpr int kWt1 = kWt0 + kWBTile;           // 43264
constexpr int kSmem = kWt1 + kWBTile;          // 51712 shorts = 103424 B
static_assert(kSmem * 2 <= 160 * 1024, "LDS within 160KiB/CU");
static_assert(kSmemMain <= kSmem, "main region fits");
static_assert(16 * 16 * kPanelStride <= kSmemMain, "x panel fits");

__global__ __launch_bounds__(512, 1) void attn_fused(
    const float* __restrict__ x,     // (4,16,256,32,32) fp32
    const float* __restrict__ rel,   // (8,16,16) fp32
    const float* __restrict__ wqkv,  // (768,256) fp32
    const float* __restrict__ bqkv,  // (768,) fp32
    const float* __restrict__ wout,  // (256,256) fp32
    const float* __restrict__ bout,  // (256,) fp32
    float* __restrict__ out) {       // (4,16,256,32,32) fp32
  __shared__ __align__(16) unsigned short smem[kSmem];
  const int tid = threadIdx.x;
  const int lane = tid & 63;
  const int wave = tid >> 6;
  const int quad = lane >> 4;
  const int lrow = lane & 15;
  const int half = lane >> 5;
  const int n32 = lane & 31;
  const int b = blockIdx.x >> 6;
  const int hw0 = (blockIdx.x & 63) * 16;

  // ---- weight staging ids + early prefetch of QKV tile 0 (fp32) ----
  const int wrow = tid >> 4;         // 0..31
  const int wcol = (tid & 15) * 16;  // 0..240
  float4 pw[4];
  {
    const float* sp = wqkv + (size_t)wrow * 256 + wcol;  // rowbase(0)=0
#pragma unroll
    for (int u = 0; u < 4; ++u) pw[u] = *(const float4*)(sp + u * 4);
  }

  // ---- phase X: stage x into bf16 panel, extract A-frags.
  // v11: chunk loads register-prefetched one chunk ahead (rx[8]).
  // ax semantics (R6-identical): A[m=n32][k=ks*16+half*8+j] =
  //   x_bf16[b][t=lrow][c=k][hw = hw0 + 2*wave + (n32>>4)]
  bf16x8 ax[16];
  {
    unsigned short* panel = smem;
    const int sloc = wave * 2 + (n32 >> 4);
    float4 rx[8];
    auto loadChunk = [&](int cc4) {
      const int c0 = cc4 * 64;
#pragma unroll
      for (int u = 0; u < 8; ++u) {
        const int idx = u * 512 + tid;
        const int row = idx >> 2;  // t*64 + cl
        const int q = idx & 3;     // which 4-hw chunk
        const int t = row >> 6;
        const int cl = row & 63;
        rx[u] = *(const float4*)(
            x + (((size_t)(b * 16 + t) * 256 + c0 + cl) << 10) + hw0 + q * 4);
      }
    };
    loadChunk(0);
#pragma unroll
    for (int cc4 = 0; cc4 < 4; ++cc4) {  // full unroll: static rx/ax indexing
      __syncthreads();  // panel free (prev chunk's readers done)
#pragma unroll
      for (int u = 0; u < 8; ++u) {
        const int idx = u * 512 + tid;
        const int row = idx >> 2;
        const int q = idx & 3;
        const int t = row >> 6;
        const int cl = row & 63;
        unsigned short* pr = panel + (t * 16 + q * 4) * kPanelStride + cl;
        pr[0] = f2bf(rx[u].x);
        pr[kPanelStride] = f2bf(rx[u].y);
        pr[2 * kPanelStride] = f2bf(rx[u].z);
        pr[3 * kPanelStride] = f2bf(rx[u].w);
      }
      if (cc4 < 3) loadChunk(cc4 + 1);  // in flight across barrier+extract
      __syncthreads();  // panel ready
#pragma unroll
      for (int kk = 0; kk < 4; ++kk)
        ax[cc4 * 4 + kk] = *(const bf16x8*)(
            panel + (lrow * 16 + sloc) * kPanelStride + kk * 16 + half * 8);
    }
  }
  // qkv_tile(0)'s first barrier protects panel region before WB0 writes.

  // ---- bias preload: 24 regs, statically indexed (heads unrolled) ----
  float bq0[8], bk0[8], bv0[8];
#pragma unroll
  for (int h = 0; h < 8; ++h) {
    bq0[h] = bqkv[h * 32 + n32];
    bk0[h] = bqkv[256 + h * 32 + n32];
    bv0[h] = bqkv[512 + h * 32 + n32];
  }

  unsigned short* qb = smem + kWB + wave * kSite;
  unsigned short* kb = qb + 640;
  unsigned short* vt = qb + 1280;  // stride 16, [d][j]

  const f32x4 zero4 = {0.f, 0.f, 0.f, 0.f};
  const float scale = 0.17677669529663687f;  // 32^-0.5
  bf16x8 ao[2][8];

  // staged QKV tile: write pw -> WB[g&1] (bf16), prefetch tile g+1 (fp32),
  // 16-kstep 32x32x16 MFMA. Barrier structure identical to R6.
  auto qkv_tile = [&](int g, float bias) -> f32x16 {
    __syncthreads();  // WB[g&1] free (consumers of g-2 done)
    unsigned short* WBc = smem + (g & 1) * kWBTile;
    {
      unsigned short* dst = WBc + wrow * kWBStride + wcol;
      uint4 a, bq;
      a.x = pack2(pw[0].x, pw[0].y);
      a.y = pack2(pw[0].z, pw[0].w);
      a.z = pack2(pw[1].x, pw[1].y);
      a.w = pack2(pw[1].z, pw[1].w);
      bq.x = pack2(pw[2].x, pw[2].y);
      bq.y = pack2(pw[2].z, pw[2].w);
      bq.z = pack2(pw[3].x, pw[3].y);
      bq.w = pack2(pw[3].z, pw[3].w);
      *(uint4*)dst = a;
      *(uint4*)(dst + 8) = bq;
    }
    {
      const int gn = g + 1;  // gn==24 -> rows 256..287: valid wqkv memory
      const int rowbase = (gn % 3) * 256 + (gn / 3) * 32;
      const float* sp = wqkv + (size_t)(rowbase + wrow) * 256 + wcol;
#pragma unroll
      for (int u = 0; u < 4; ++u) pw[u] = *(const float4*)(sp + u * 4);
    }
    __syncthreads();  // WB[g&1] ready
    f32x16 acc;
#pragma unroll
    for (int i = 0; i < 16; ++i) acc[i] = bias;
    const unsigned short* br = WBc + n32 * kWBStride + half * 8;
#pragma unroll
    for (int ks = 0; ks < 16; ++ks) {
      const bf16x8 bf = *(const bf16x8*)(br + ks * 16);
      acc = __builtin_amdgcn_mfma_f32_32x32x16_bf16(ax[ks], bf, acc, 0, 0, 0);
    }
    return acc;
  };

  // one head, h literal at each call site (R6-identical body, reg biases)
  auto head_body = [&](int h) {
    const f32x16 qacc = qkv_tile(h * 3 + 0, bq0[h]);
    const f32x16 kacc = qkv_tile(h * 3 + 1, bk0[h]);
    const f32x16 vacc = qkv_tile(h * 3 + 2, bv0[h]);
    float rl[4];
#pragma unroll
    for (int r = 0; r < 4; ++r) rl[r] = rel[h * 256 + (quad * 4 + r) * 16 + lrow];

#pragma unroll
    for (int s = 0; s < 2; ++s) {
      // C/D 32x32: reg=8s+rr -> row=16s+t, t=(rr&3)+8*(rr>>2)+4*half, col=n32
#pragma unroll
      for (int rr = 0; rr < 8; ++rr) {
        const int t = (rr & 3) + 8 * (rr >> 2) + 4 * half;
        qb[t * 40 + n32] = f2bf(qacc[8 * s + rr]);
        kb[t * 40 + n32] = f2bf(kacc[8 * s + rr]);
      }
#pragma unroll
      for (int rp = 0; rp < 4; ++rp) {  // vT[d][j], paired t writes (b32)
        const int rr = rp * 2;
        const int t = (rr & 3) + 8 * (rr >> 2) + 4 * half;
        *(unsigned int*)&vt[n32 * 16 + t] =
            pack2(vacc[8 * s + rr], vacc[8 * s + rr + 1]);
      }
      // sim (16x16x32): A=q[m=t][k=d], B[k=d][n=j]=k[j][d]
      const bf16x8 qf = *(const bf16x8*)(qb + lrow * 40 + quad * 8);
      const bf16x8 kf = *(const bf16x8*)(kb + lrow * 40 + quad * 8);
      const f32x4 sim = __builtin_amdgcn_mfma_f32_16x16x32_bf16(qf, kf, zero4, 0, 0, 0);
      float p[4], inv[4];
#pragma unroll
      for (int r = 0; r < 4; ++r) {
        const float v = sim[r] * scale + rl[r];
        float m = v;
        for (int off = 8; off; off >>= 1) m = fmaxf(m, __shfl_xor(m, off));
        const float e = __expf(v - m);
        float sum = e;
        for (int off = 8; off; off >>= 1) sum += __shfl_xor(sum, off);
        p[r] = e;
        inv[r] = 1.0f / sum;
      }
      unsigned short* pb = kb;  // P overlays k (dead), stride 24
#pragma unroll
      for (int r = 0; r < 4; ++r) pb[(quad * 4 + r) * 24 + lrow] = f2bf(p[r]);
      bf16x8 pf, vf0, vf1;
      if (quad < 2) {
        pf = *(const bf16x8*)(pb + lrow * 24 + quad * 8);
        vf0 = *(const bf16x8*)(vt + lrow * 16 + quad * 8);
        vf1 = *(const bf16x8*)(vt + (16 + lrow) * 16 + quad * 8);
      } else {
#pragma unroll
        for (int j = 0; j < 8; ++j) { pf[j] = 0; vf0[j] = 0; vf1[j] = 0; }
      }
      const f32x4 o0 = __builtin_amdgcn_mfma_f32_16x16x32_bf16(pf, vf0, zero4, 0, 0, 0);
      const f32x4 o1 = __builtin_amdgcn_mfma_f32_16x16x32_bf16(pf, vf1, zero4, 0, 0, 0);
#pragma unroll
      for (int r = 0; r < 4; ++r) {  // O bounce into qb (dead) -> A-layout
        const int t = quad * 4 + r;
        qb[t * 40 + lrow] = f2bf(o0[r] * inv[r]);
        qb[t * 40 + 16 + lrow] = f2bf(o1[r] * inv[r]);
      }
      ao[s][h] = *(const bf16x8*)(qb + lrow * 40 + quad * 8);
    }
  };

  // fully unrolled heads: literal h -> ao[][] statically indexed (registers)
  head_body(0);
  head_body(1);
  head_body(2);
  head_body(3);
  head_body(4);
  head_body(5);
  head_body(6);
  head_body(7);

  // ---- epilogue: y = O @ wout^T + bout. v11 pipeline:
  // dbuf wtile(wt0/wt1) + dbuf fbuf(fb0/fb1), wout reg-prefetch one cc
  // ahead, fully unrolled (static indices), ONE barrier per segment.
  // Segment i: MFMA cc=i from wt[i&1] -> fb[i&1]; write wt[(i+1)&1] from
  // prefetched regs; issue prefetch cc=i+2; stores of cc=i-1 from
  // fb[(i-1)&1] (overlapping the MFMAs); barrier.
  float* fb0 = (float*)smem;            // 8704 floats
  float* fb1 = (float*)(smem + kFb1);   // 8704 floats
  unsigned short* wt0 = smem + kWt0;    // 32 x 264 bf16
  unsigned short* wt1 = smem + kWt1;

  float4 pwe[4];
  auto loadWout = [&](int cc) {
    const float* sp = wout + (size_t)(cc * 32 + wrow) * 256 + wcol;
#pragma unroll
    for (int u = 0; u < 4; ++u) pwe[u] = *(const float4*)(sp + u * 4);
  };
  auto writeWt = [&](unsigned short* wt) {
    uint4 a, bq;
    a.x = pack2(pwe[0].x, pwe[0].y);
    a.y = pack2(pwe[0].z, pwe[0].w);
    a.z = pack2(pwe[1].x, pwe[1].y);
    a.w = pack2(pwe[1].z, pwe[1].w);
    bq.x = pack2(pwe[2].x, pwe[2].y);
    bq.y = pack2(pwe[2].z, pwe[2].w);
    bq.z = pack2(pwe[3].x, pwe[3].y);
    bq.w = pack2(pwe[3].z, pwe[3].w);
    unsigned short* d = wt + wrow * kWBStride + wcol;
    *(uint4*)d = a;
    *(uint4*)(d + 8) = bq;
  };

  float bo0[8], bo1[8];
#pragma unroll
  for (int cc = 0; cc < 8; ++cc) {
    bo0[cc] = bout[cc * 32 + lrow];
    bo1[cc] = bout[cc * 32 + 16 + lrow];
  }

  // prologue: wt0/wt1 region is disjoint from main-loop smem [0,31488):
  // safe to write before the barrier. fb region overlays WB+sites.
  loadWout(0);
  writeWt(wt0);
  loadWout(1);
  __syncthreads();  // sites dead + wt0 visible to all

  float* ob = out + ((size_t)b << 22);
  auto epi = [&](int i) {  // i literal at each call site
    if (i < 8) {
      unsigned short* wt = (i & 1) ? wt1 : wt0;
      float* fb = (i & 1) ? fb1 : fb0;
#pragma unroll
      for (int sub = 0; sub < 2; ++sub) {
        const float bias = sub ? bo1[i] : bo0[i];
        f32x4 y0 = {bias, bias, bias, bias};
        f32x4 y1 = {bias, bias, bias, bias};
        const unsigned short* wrp = wt + (sub * 16 + lrow) * kWBStride;
#pragma unroll
        for (int ks = 0; ks < 8; ++ks) {
          const bf16x8 wf = *(const bf16x8*)(wrp + ks * 32 + quad * 8);
          y0 = __builtin_amdgcn_mfma_f32_16x16x32_bf16(ao[0][ks], wf, y0, 0, 0, 0);
          y1 = __builtin_amdgcn_mfma_f32_16x16x32_bf16(ao[1][ks], wf, y1, 0, 0, 0);
        }
#pragma unroll
        for (int r = 0; r < 4; ++r) {
          const int L = ((quad * 4 + r) * 32 + sub * 16 + lrow) * 17 + wave * 2;
          fb[L] = y0[r];
          fb[L + 1] = y1[r];
        }
      }
      if (i < 7) writeWt((i & 1) ? wt0 : wt1);  // tile i+1 -> parity (i+1)&1
      if (i < 6) loadWout(i + 2);
    }
    if (i > 0) {  // stores of cc=i-1, overlapping this segment's MFMAs
      const int cc = i - 1;
      float* fb = ((i - 1) & 1) ? fb1 : fb0;
      const int t = tid >> 5, cl = tid & 31;
      float v[16];
#pragma unroll
      for (int u = 0; u < 16; ++u) v[u] = fb[tid * 17 + u];
      float* dst = ob + ((size_t)(t * 256 + cc * 32 + cl)) * 1024 + hw0;
#pragma unroll
      for (int u = 0; u < 4; ++u) {
        float4 q;
        q.x = v[u * 4]; q.y = v[u * 4 + 1]; q.z = v[u * 4 + 2]; q.w = v[u * 4 + 3];
        *(float4*)(dst + u * 4) = q;
      }
    }
    if (i < 8) __syncthreads();  // fb[i&1] ready; wt[(i+1)&1] ready;
                                 // stores(i-1)'s fb reads drained
  };
  epi(0); epi(1); epi(2); epi(3); epi(4); epi(5); epi(6); epi(7); epi(8);
}

}  // namespace

extern "C" void kernel_launch(void* const* d_in, const int* in_sizes, int n_in,
                              void* d_out, int out_size, void* d_ws, size_t ws_size,
                              hipStream_t stream) {
  const float* x = (const float*)d_in[0];
  const float* rel = (const float*)d_in[1];
  const float* wqkv = (const float*)d_in[2];
  const float* bqkv = (const float*)d_in[3];
  const float* wout = (const float*)d_in[4];
  const float* bout = (const float*)d_in[5];
  float* out = (float*)d_out;
  (void)in_sizes; (void)n_in; (void)out_size; (void)d_ws; (void)ws_size;

  attn_fused<<<256, 512, 0, stream>>>(x, rel, wqkv, bqkv, wout, bout, out);
}

// Round 11
// 203.283 us; speedup vs baseline: 1.2851x; 1.0990x over previous
//
#include <hip/hip_runtime.h>
#include <hip/hip_bf16.h>

typedef __attribute__((ext_vector_type(8))) short bf16x8;
typedef __attribute__((ext_vector_type(4))) float f32x4;

namespace {

__device__ __forceinline__ unsigned short f2bf(float f) {
  unsigned int x;
  __builtin_memcpy(&x, &f, 4);
  x += 0x7fff + ((x >> 16) & 1);  // round-to-nearest-even
  return (unsigned short)(x >> 16);
}
__device__ __forceinline__ unsigned int pack2(float a, float b) {
  return (unsigned int)f2bf(a) | ((unsigned int)f2bf(b) << 16);
}

// ============================ fused kernel ============================
// v12: the one untested lever -- waves/SIMD. R4 reached 16 waves/CU but was
// confounded by a 64-VGPR cap (spill everywhere, still 159us). Here:
// 1024 thr = 16 waves (4/SIMD, 2x R6's hiding), wave = ONE site via the
// VERIFIED fallback kernel's m=16 math (fits the 128-VGPR cap:
// ax[8]=32 + ao[8]=32 + pw 8 + accs ~ 100). __launch_bounds__(1024,4)
// pins the cap at 128 with exactly 1 block/CU. Staging = R6's proven
// 2-barrier dbuf reg-staged tiles; phase X = R6 panel (m=16 extract);
// epilogue = R6 per-cc wtile+fbuf (fbuf line +wave = 16 hw exactly).
constexpr int kWBStride = 264;                 // 256 + 8 pad (elems)
constexpr int kWBTile = 32 * kWBStride;        // 8448 elems
constexpr int kWB = 2 * kWBTile;               // 16896 elems
constexpr int kSite = 1792;                    // qb512|kbuf512|vtb512|pb256 (fallback layout)
constexpr int kSmem = kWB + 16 * kSite;        // 45568 shorts = 91136 B
constexpr int kPanelStride = 72;               // x-panel row stride (16B-aligned b128)
constexpr int kWTileOff = 34816;               // shorts; after fbuf (512*17 floats)
static_assert(kSmem * 2 <= 160 * 1024, "LDS budget");
static_assert(16 * 16 * kPanelStride <= kSmem, "x panel fits");
static_assert(512 * 17 * 4 <= kSmem * 2, "fbuf fits");
static_assert(kWTileOff + kWBTile <= kSmem, "wout tile fits after fbuf");

__global__ __launch_bounds__(1024, 4) void attn_fused(
    const float* __restrict__ x,     // (4,16,256,32,32) fp32
    const float* __restrict__ rel,   // (8,16,16) fp32
    const float* __restrict__ wqkv,  // (768,256) fp32
    const float* __restrict__ bqkv,  // (768,) fp32
    const float* __restrict__ wout,  // (256,256) fp32
    const float* __restrict__ bout,  // (256,) fp32
    float* __restrict__ out) {       // (4,16,256,32,32) fp32
  __shared__ __align__(16) unsigned short smem[kSmem];
  const int tid = threadIdx.x;
  const int lane = tid & 63;
  const int wave = tid >> 6;   // 0..15 -- this wave's hw site
  const int quad = lane >> 4;
  const int lrow = lane & 15;
  const int b = blockIdx.x >> 6;
  const int hw0 = (blockIdx.x & 63) * 16;

  // ---- weight staging ids + early prefetch of QKV tile 0 (fp32) ----
  // tile g rows = wqkv rows (g%3)*256 + (g/3)*32 .. +32 (valid for g<=24)
  const int wrow = tid >> 5;         // 0..31
  const int wcol = (tid & 31) * 8;   // 0..248
  float4 pw[2];
  {
    const float* sp = wqkv + (size_t)wrow * 256 + wcol;  // rowbase(0)=0
    pw[0] = ((const float4*)sp)[0];
    pw[1] = ((const float4*)sp)[1];
  }

  // ---- phase X: stage x into bf16 panel, extract A-frags (m=16) ----
  // ax semantics (fallback-identical): ax[ks][j] =
  //   x_bf16[b][t=lrow][c=ks*32+quad*8+j][hw = hw0 + wave]
  bf16x8 ax[8];
  {
    unsigned short* panel = smem;
#pragma unroll
    for (int cc4 = 0; cc4 < 4; ++cc4) {  // full unroll: ax statically indexed
      const int c0 = cc4 * 64;
      __syncthreads();  // panel free (prev chunk's readers done)
#pragma unroll
      for (int u = 0; u < 4; ++u) {
        const int idx = u * 1024 + tid;
        const int row = idx >> 2;  // t*64 + cl
        const int q = idx & 3;     // which 4-hw chunk
        const int t = row >> 6;
        const int cl = row & 63;
        const float4 v = *(const float4*)(
            x + (((size_t)(b * 16 + t) * 256 + c0 + cl) << 10) + hw0 + q * 4);
        unsigned short* pr = panel + (t * 16 + q * 4) * kPanelStride + cl;
        pr[0] = f2bf(v.x);
        pr[kPanelStride] = f2bf(v.y);
        pr[2 * kPanelStride] = f2bf(v.z);
        pr[3 * kPanelStride] = f2bf(v.w);
      }
      __syncthreads();  // panel ready
#pragma unroll
      for (int kk = 0; kk < 2; ++kk)
        ax[cc4 * 2 + kk] = *(const bf16x8*)(
            panel + (lrow * 16 + wave) * kPanelStride + kk * 32 + quad * 8);
    }
  }
  // qkv_tile(0)'s first barrier protects panel region before WB0 writes.

  unsigned short* qb = smem + kWB + wave * kSite;
  unsigned short* kbuf = qb + 512;
  unsigned short* vtb = qb + 1024;
  unsigned short* pb = qb + 1536;

  const f32x4 zero4 = {0.f, 0.f, 0.f, 0.f};
  const float scale = 0.17677669529663687f;  // 32^-0.5
  bf16x8 ao[8];

  // one (head, sel) tile: dbuf stage from regs, prefetch g+1, fallback MFMA
  auto qkv_tile = [&](int g, int h, int sel) {
    __syncthreads();  // WB[g&1] free (consumers of g-2 done)
    unsigned short* WBc = smem + (g & 1) * kWBTile;
    {
      uint4 a;
      a.x = pack2(pw[0].x, pw[0].y);
      a.y = pack2(pw[0].z, pw[0].w);
      a.z = pack2(pw[1].x, pw[1].y);
      a.w = pack2(pw[1].z, pw[1].w);
      *(uint4*)(WBc + wrow * kWBStride + wcol) = a;
    }
    {
      const int gn = g + 1;  // gn==24 -> rows 256..287: valid wqkv memory
      const int rowbase = (gn % 3) * 256 + (gn / 3) * 32;
      const float* sp = wqkv + (size_t)(rowbase + wrow) * 256 + wcol;
      pw[0] = ((const float4*)sp)[0];
      pw[1] = ((const float4*)sp)[1];
    }
    __syncthreads();  // WB[g&1] ready
    const float bias0 = bqkv[sel * 256 + h * 32 + lrow];
    const float bias1 = bqkv[sel * 256 + h * 32 + 16 + lrow];
    f32x4 acc0 = {bias0, bias0, bias0, bias0};
    f32x4 acc1 = {bias1, bias1, bias1, bias1};
#pragma unroll
    for (int ks = 0; ks < 8; ++ks) {
      const bf16x8 b0 =
          *(const bf16x8*)(WBc + lrow * kWBStride + ks * 32 + quad * 8);
      const bf16x8 b1 =
          *(const bf16x8*)(WBc + (16 + lrow) * kWBStride + ks * 32 + quad * 8);
      acc0 = __builtin_amdgcn_mfma_f32_16x16x32_bf16(ax[ks], b0, acc0, 0, 0, 0);
      acc1 = __builtin_amdgcn_mfma_f32_16x16x32_bf16(ax[ks], b1, acc1, 0, 0, 0);
    }
    // write-back (fallback-identical)
    if (sel < 2) {
      unsigned short* dst = sel ? kbuf : qb;
#pragma unroll
      for (int r = 0; r < 4; ++r) {
        const int row = quad * 4 + r;
        dst[row * 32 + lrow] = f2bf(acc0[r]);
        dst[row * 32 + 16 + lrow] = f2bf(acc1[r]);
      }
    } else {
#pragma unroll
      for (int r = 0; r < 4; ++r) {
        const int row = quad * 4 + r;
        vtb[lrow * 16 + row] = f2bf(acc0[r]);
        vtb[(16 + lrow) * 16 + row] = f2bf(acc1[r]);
      }
    }
  };

  // one head, h literal at each call site (fallback-identical attention)
  auto head_body = [&](int h) {
    qkv_tile(h * 3 + 0, h, 0);
    qkv_tile(h * 3 + 1, h, 1);
    qkv_tile(h * 3 + 2, h, 2);

    const bf16x8 qf = *(const bf16x8*)&qb[lrow * 32 + quad * 8];
    const bf16x8 kf = *(const bf16x8*)&kbuf[lrow * 32 + quad * 8];
    const f32x4 sim = __builtin_amdgcn_mfma_f32_16x16x32_bf16(qf, kf, zero4, 0, 0, 0);
    float p[4], inv[4];
#pragma unroll
    for (int r = 0; r < 4; ++r) {
      const int i = quad * 4 + r;
      const float v = sim[r] * scale + rel[h * 256 + i * 16 + lrow];
      float m = v;
      for (int off = 8; off; off >>= 1) m = fmaxf(m, __shfl_xor(m, off));
      const float e = __expf(v - m);
      float s = e;
      for (int off = 8; off; off >>= 1) s += __shfl_xor(s, off);
      p[r] = e;
      inv[r] = 1.0f / s;
    }
#pragma unroll
    for (int r = 0; r < 4; ++r) pb[(quad * 4 + r) * 16 + lrow] = f2bf(p[r]);
    bf16x8 pf, vf0, vf1;
    if (quad < 2) {
      pf = *(const bf16x8*)&pb[lrow * 16 + quad * 8];
      vf0 = *(const bf16x8*)&vtb[lrow * 16 + quad * 8];
      vf1 = *(const bf16x8*)&vtb[(16 + lrow) * 16 + quad * 8];
    } else {
#pragma unroll
      for (int j = 0; j < 8; ++j) { pf[j] = 0; vf0[j] = 0; vf1[j] = 0; }
    }
    const f32x4 o0 = __builtin_amdgcn_mfma_f32_16x16x32_bf16(pf, vf0, zero4, 0, 0, 0);
    const f32x4 o1 = __builtin_amdgcn_mfma_f32_16x16x32_bf16(pf, vf1, zero4, 0, 0, 0);
#pragma unroll
    for (int r = 0; r < 4; ++r) {  // O bounce into qb (dead) -> A-layout
      const int t = quad * 4 + r;
      qb[t * 32 + lrow] = f2bf(o0[r] * inv[r]);
      qb[t * 32 + 16 + lrow] = f2bf(o1[r] * inv[r]);
    }
    ao[h] = *(const bf16x8*)&qb[lrow * 32 + quad * 8];
  };

  // fully unrolled heads: literal h -> ao[] statically indexed (registers)
  head_body(0);
  head_body(1);
  head_body(2);
  head_body(3);
  head_body(4);
  head_body(5);
  head_body(6);
  head_body(7);

  // ---- epilogue: y = O @ wout^T + bout ----
  // Per cc: stage wout rows cc*32..+32 once to LDS bf16 (8 f2bf/thread),
  // m=16 MFMA per wave/site, fbuf line (t*32+c_l)*17 + wave (16 hw),
  // 64-B coalesced stores (2 threads per line-half).
  __syncthreads();  // sitebufs/WB dead; fbuf+wtile overlay smem
  float* fbuf = (float*)smem;                 // 512 lines x 17 floats
  unsigned short* wtile = smem + kWTileOff;   // 32 x 264 bf16
  float* ob = out + ((size_t)b << 22);
#pragma unroll 1
  for (int cc = 0; cc < 8; ++cc) {
    {
      const float* sp = wout + (size_t)(cc * 32 + wrow) * 256 + wcol;
      const float4 v0 = ((const float4*)sp)[0];
      const float4 v1 = ((const float4*)sp)[1];
      uint4 a;
      a.x = pack2(v0.x, v0.y);
      a.y = pack2(v0.z, v0.w);
      a.z = pack2(v1.x, v1.y);
      a.w = pack2(v1.z, v1.w);
      *(uint4*)(wtile + wrow * kWBStride + wcol) = a;
    }
    __syncthreads();  // wtile ready
#pragma unroll
    for (int sub = 0; sub < 2; ++sub) {
      const int c = cc * 32 + sub * 16 + lrow;
      const float bias = bout[c];
      f32x4 y = {bias, bias, bias, bias};
      const unsigned short* wrp = wtile + (sub * 16 + lrow) * kWBStride;
#pragma unroll
      for (int ks = 0; ks < 8; ++ks) {
        const bf16x8 wf = *(const bf16x8*)(wrp + ks * 32 + quad * 8);
        y = __builtin_amdgcn_mfma_f32_16x16x32_bf16(ao[ks], wf, y, 0, 0, 0);
      }
#pragma unroll
      for (int r = 0; r < 4; ++r) {
        const int t = quad * 4 + r;
        fbuf[(t * 32 + sub * 16 + lrow) * 17 + wave] = y[r];
      }
    }
    __syncthreads();
    {
      const int L = tid >> 1, hf = tid & 1;  // line, half
      const int t = L >> 5, cl = L & 31;
      float v[8];
#pragma unroll
      for (int i = 0; i < 8; ++i) v[i] = fbuf[L * 17 + hf * 8 + i];
      float* dst = ob + ((size_t)(t * 256 + cc * 32 + cl)) * 1024 + hw0 + hf * 8;
      float4 s0, s1;
      s0.x = v[0]; s0.y = v[1]; s0.z = v[2]; s0.w = v[3];
      s1.x = v[4]; s1.y = v[5]; s1.z = v[6]; s1.w = v[7];
      *(float4*)dst = s0;
      *(float4*)(dst + 4) = s1;
    }
    __syncthreads();  // fbuf+wtile free for next cc
  }
}

}  // namespace

extern "C" void kernel_launch(void* const* d_in, const int* in_sizes, int n_in,
                              void* d_out, int out_size, void* d_ws, size_t ws_size,
                              hipStream_t stream) {
  const float* x = (const float*)d_in[0];
  const float* rel = (const float*)d_in[1];
  const float* wqkv = (const float*)d_in[2];
  const float* bqkv = (const float*)d_in[3];
  const float* wout = (const float*)d_in[4];
  const float* bout = (const float*)d_in[5];
  float* out = (float*)d_out;
  (void)in_sizes; (void)n_in; (void)out_size; (void)d_ws; (void)ws_size;

  attn_fused<<<256, 1024, 0, stream>>>(x, rel, wqkv, bqkv, wout, bout, out);
}

// Round 12
// 199.844 us; speedup vs baseline: 1.3072x; 1.0172x over previous
//
#include <hip/hip_runtime.h>
#include <hip/hip_bf16.h>

typedef __attribute__((ext_vector_type(8))) short bf16x8;
typedef __attribute__((ext_vector_type(4))) float f32x4;
typedef __attribute__((ext_vector_type(16))) float f32x16;

namespace {

__device__ __forceinline__ unsigned short f2bf(float f) {
  unsigned int x;
  __builtin_memcpy(&x, &f, 4);
  x += 0x7fff + ((x >> 16) & 1);  // round-to-nearest-even
  return (unsigned short)(x >> 16);
}
__device__ __forceinline__ unsigned int pack2(float a, float b) {
  return (unsigned int)f2bf(a) | ((unsigned int)f2bf(b) << 16);
}

// ============================ fused kernel ============================
// v13 = v7/R6 (proven best: 111us) + two ZERO-REGISTER code motions that
// change only WHERE latency is drained (R11 closed the occupancy question:
// 4 waves/SIMD, clean registers, 116us -- null):
//  (1) next-tile weight prefetch moved AFTER barrier B. R6 issued it
//      between A and B, so B's compiler-emitted s_waitcnt vmcnt(0) drained
//      it immediately -- full L2 latency exposed 24x. Now it drains at the
//      NEXT tile's barrier A, hidden under 16 MFMAs + softmax.
//  (2) bqkv biases stashed to LDS once (during phase X); each tile reads
//      its bias between A and B -- that ds_read is drained by B's existing
//      lgkmcnt(0) at zero marginal cost, so acc-init no longer waits on a
//      global load. LDS 62976 -> 66048 B (>64KB proven safe, R7; grid=256
//      keeps 1 block/CU regardless).
constexpr int kWBStride = 264;                 // 256 + 8 pad (elems)
constexpr int kWBTile = 32 * kWBStride;        // 8448 elems
constexpr int kWB = 2 * kWBTile;               // 16896 elems
constexpr int kSite = 1824;                    // q640(s40)|k640(s40,P s24)|vt512(s16)|pad
constexpr int kBiasOff = kWB + 8 * kSite;      // 31488 shorts
constexpr int kSmem = kBiasOff + 1536;         // + 768 floats = 33024 shorts = 66048 B
constexpr int kPanelStride = 72;               // (t,hw) row stride; 144B: 16B-aligned b128 reads
constexpr int kWTileOff = 17408;               // shorts; after fbuf (512*17 floats)
static_assert(kSmem * 2 <= 160 * 1024, "LDS budget (1 block/CU by grid)");
static_assert(16 * 16 * kPanelStride <= kBiasOff, "x panel below bias region");
static_assert(512 * 17 * 4 <= kSmem * 2, "fbuf fits");
static_assert(kWTileOff + kWBTile <= kBiasOff, "wout tile fits after fbuf");

__global__ __launch_bounds__(512, 1) void attn_fused(
    const float* __restrict__ x,     // (4,16,256,32,32) fp32
    const float* __restrict__ rel,   // (8,16,16) fp32
    const float* __restrict__ wqkv,  // (768,256) fp32
    const float* __restrict__ bqkv,  // (768,) fp32
    const float* __restrict__ wout,  // (256,256) fp32
    const float* __restrict__ bout,  // (256,) fp32
    float* __restrict__ out) {       // (4,16,256,32,32) fp32
  __shared__ __align__(16) unsigned short smem[kSmem];
  const int tid = threadIdx.x;
  const int lane = tid & 63;
  const int wave = tid >> 6;
  const int quad = lane >> 4;
  const int lrow = lane & 15;
  const int half = lane >> 5;
  const int n32 = lane & 31;
  const int b = blockIdx.x >> 6;
  const int hw0 = (blockIdx.x & 63) * 16;
  float* bLds = (float*)(smem + kBiasOff);

  // ---- weight staging ids + early prefetch of QKV tile 0 (fp32) ----
  // tile g rows = wqkv rows (g%3)*256 + (g/3)*32 .. +32 (valid for g<=24)
  const int wrow = tid >> 4;         // 0..31
  const int wcol = (tid & 15) * 16;  // 0..240
  float4 pw[4];
  {
    const float* sp = wqkv + (size_t)wrow * 256 + wcol;  // rowbase(0)=0
#pragma unroll
    for (int u = 0; u < 4; ++u) pw[u] = *(const float4*)(sp + u * 4);
  }

  // ---- bias stash: 768 floats -> LDS (read during main loop between A/B) ----
  for (int i = tid; i < 768; i += 512) bLds[i] = bqkv[i];

  // ---- phase X: stage x into bf16 panel, extract A-frags (R6-identical) ----
  // ax semantics: A[m=n32][k=ks*16+half*8+j] =
  //   x_bf16[b][t=lrow][c=k][hw = hw0 + 2*wave + (n32>>4)]
  bf16x8 ax[16];
  {
    unsigned short* panel = smem;
    const int sloc = wave * 2 + (n32 >> 4);
#pragma unroll
    for (int cc4 = 0; cc4 < 4; ++cc4) {  // full unroll: ax statically indexed
      const int c0 = cc4 * 64;
      __syncthreads();  // panel free (prev chunk's readers done)
#pragma unroll
      for (int u = 0; u < 8; ++u) {
        const int idx = u * 512 + tid;
        const int row = idx >> 2;  // t*64 + cl
        const int q = idx & 3;     // which 4-hw chunk
        const int t = row >> 6;
        const int cl = row & 63;
        const float4 v = *(const float4*)(
            x + (((size_t)(b * 16 + t) * 256 + c0 + cl) << 10) + hw0 + q * 4);
        unsigned short* pr = panel + (t * 16 + q * 4) * kPanelStride + cl;
        pr[0] = f2bf(v.x);
        pr[kPanelStride] = f2bf(v.y);
        pr[2 * kPanelStride] = f2bf(v.z);
        pr[3 * kPanelStride] = f2bf(v.w);
      }
      __syncthreads();  // panel ready
#pragma unroll
      for (int kk = 0; kk < 4; ++kk)
        ax[cc4 * 4 + kk] = *(const bf16x8*)(
            panel + (lrow * 16 + sloc) * kPanelStride + kk * 16 + half * 8);
    }
  }
  // qkv_tile(0)'s first barrier protects panel region before WB0 writes.

  unsigned short* qb = smem + kWB + wave * kSite;
  unsigned short* kb = qb + 640;
  unsigned short* vt = qb + 1280;  // stride 16, [d][j]

  const f32x4 zero4 = {0.f, 0.f, 0.f, 0.f};
  const float scale = 0.17677669529663687f;  // 32^-0.5
  bf16x8 ao[2][8];

  // staged QKV tile: write pw -> WB[g&1] (bf16); bias ds_read between A/B
  // (drained by B's existing lgkmcnt(0)); prefetch tile g+1 issued AFTER B
  // so its vmcnt drain lands at the NEXT tile's barrier A (hidden under
  // the 16-MFMA phase); 16-kstep 32x32x16 MFMA.
  auto qkv_tile = [&](int g, int bidx) -> f32x16 {
    __syncthreads();  // A: WB[g&1] free (consumers of g-2 done)
    unsigned short* WBc = smem + (g & 1) * kWBTile;
    {
      unsigned short* dst = WBc + wrow * kWBStride + wcol;
      uint4 a, bq;
      a.x = pack2(pw[0].x, pw[0].y);
      a.y = pack2(pw[0].z, pw[0].w);
      a.z = pack2(pw[1].x, pw[1].y);
      a.w = pack2(pw[1].z, pw[1].w);
      bq.x = pack2(pw[2].x, pw[2].y);
      bq.y = pack2(pw[2].z, pw[2].w);
      bq.z = pack2(pw[3].x, pw[3].y);
      bq.w = pack2(pw[3].z, pw[3].w);
      *(uint4*)dst = a;
      *(uint4*)(dst + 8) = bq;
    }
    const float bias = bLds[bidx];  // lgkm, drained at B anyway
    __syncthreads();  // B: WB[g&1] ready
    {
      // prefetch AFTER the barrier: in flight across the MFMA phase
      const int gn = g + 1;  // gn==24 -> rows 256..287: valid wqkv memory
      const int rowbase = (gn % 3) * 256 + (gn / 3) * 32;
      const float* sp = wqkv + (size_t)(rowbase + wrow) * 256 + wcol;
#pragma unroll
      for (int u = 0; u < 4; ++u) pw[u] = *(const float4*)(sp + u * 4);
    }
    f32x16 acc;
#pragma unroll
    for (int i = 0; i < 16; ++i) acc[i] = bias;
    const unsigned short* br = WBc + n32 * kWBStride + half * 8;
#pragma unroll
    for (int ks = 0; ks < 16; ++ks) {
      const bf16x8 bf = *(const bf16x8*)(br + ks * 16);
      acc = __builtin_amdgcn_mfma_f32_32x32x16_bf16(ax[ks], bf, acc, 0, 0, 0);
    }
    return acc;
  };

  // one head, h literal at each call site (R6-identical body)
  auto head_body = [&](int h) {
    const f32x16 qacc = qkv_tile(h * 3 + 0, h * 32 + n32);
    const f32x16 kacc = qkv_tile(h * 3 + 1, 256 + h * 32 + n32);
    const f32x16 vacc = qkv_tile(h * 3 + 2, 512 + h * 32 + n32);
    float rl[4];
#pragma unroll
    for (int r = 0; r < 4; ++r) rl[r] = rel[h * 256 + (quad * 4 + r) * 16 + lrow];

#pragma unroll
    for (int s = 0; s < 2; ++s) {
      // C/D 32x32: reg=8s+rr -> row=16s+t, t=(rr&3)+8*(rr>>2)+4*half, col=n32
#pragma unroll
      for (int rr = 0; rr < 8; ++rr) {
        const int t = (rr & 3) + 8 * (rr >> 2) + 4 * half;
        qb[t * 40 + n32] = f2bf(qacc[8 * s + rr]);
        kb[t * 40 + n32] = f2bf(kacc[8 * s + rr]);
      }
#pragma unroll
      for (int rp = 0; rp < 4; ++rp) {  // vT[d][j], paired t writes (b32)
        const int rr = rp * 2;
        const int t = (rr & 3) + 8 * (rr >> 2) + 4 * half;
        *(unsigned int*)&vt[n32 * 16 + t] =
            pack2(vacc[8 * s + rr], vacc[8 * s + rr + 1]);
      }
      // sim (16x16x32): A=q[m=t][k=d], B[k=d][n=j]=k[j][d]
      const bf16x8 qf = *(const bf16x8*)(qb + lrow * 40 + quad * 8);
      const bf16x8 kf = *(const bf16x8*)(kb + lrow * 40 + quad * 8);
      const f32x4 sim = __builtin_amdgcn_mfma_f32_16x16x32_bf16(qf, kf, zero4, 0, 0, 0);
      float p[4], inv[4];
#pragma unroll
      for (int r = 0; r < 4; ++r) {
        const float v = sim[r] * scale + rl[r];
        float m = v;
        for (int off = 8; off; off >>= 1) m = fmaxf(m, __shfl_xor(m, off));
        const float e = __expf(v - m);
        float sum = e;
        for (int off = 8; off; off >>= 1) sum += __shfl_xor(sum, off);
        p[r] = e;
        inv[r] = 1.0f / sum;
      }
      unsigned short* pb = kb;  // P overlays k (dead), stride 24
#pragma unroll
      for (int r = 0; r < 4; ++r) pb[(quad * 4 + r) * 24 + lrow] = f2bf(p[r]);
      bf16x8 pf, vf0, vf1;
      if (quad < 2) {
        pf = *(const bf16x8*)(pb + lrow * 24 + quad * 8);
        vf0 = *(const bf16x8*)(vt + lrow * 16 + quad * 8);
        vf1 = *(const bf16x8*)(vt + (16 + lrow) * 16 + quad * 8);
      } else {
#pragma unroll
        for (int j = 0; j < 8; ++j) { pf[j] = 0; vf0[j] = 0; vf1[j] = 0; }
      }
      const f32x4 o0 = __builtin_amdgcn_mfma_f32_16x16x32_bf16(pf, vf0, zero4, 0, 0, 0);
      const f32x4 o1 = __builtin_amdgcn_mfma_f32_16x16x32_bf16(pf, vf1, zero4, 0, 0, 0);
#pragma unroll
      for (int r = 0; r < 4; ++r) {  // O bounce into qb (dead) -> A-layout
        const int t = quad * 4 + r;
        qb[t * 40 + lrow] = f2bf(o0[r] * inv[r]);
        qb[t * 40 + 16 + lrow] = f2bf(o1[r] * inv[r]);
      }
      ao[s][h] = *(const bf16x8*)(qb + lrow * 40 + quad * 8);
    }
  };

  // fully unrolled heads: literal h -> ao[][] statically indexed (registers)
  head_body(0);
  head_body(1);
  head_body(2);
  head_body(3);
  head_body(4);
  head_body(5);
  head_body(6);
  head_body(7);

  // ---- epilogue: y = O @ wout^T + bout (R6-identical) ----
  // Per cc: stage wout rows cc*32..+32 once to LDS bf16 (16 f2bf/thread),
  // MFMA reads b128 from padded tile, fbuf bounce, 64-B coalesced stores.
  __syncthreads();  // sitebufs/WB dead; fbuf+wtile overlay smem
  float* fbuf = (float*)smem;                 // 512 lines x 17 floats
  unsigned short* wtile = smem + kWTileOff;   // 32 x 264 bf16
  float* ob = out + ((size_t)b << 22);
#pragma unroll 1
  for (int cc = 0; cc < 8; ++cc) {
    {
      const float* sp = wout + (size_t)(cc * 32 + wrow) * 256 + wcol;
      const float4 v0 = ((const float4*)sp)[0];
      const float4 v1 = ((const float4*)sp)[1];
      const float4 v2 = ((const float4*)sp)[2];
      const float4 v3 = ((const float4*)sp)[3];
      uint4 a, bq;
      a.x = pack2(v0.x, v0.y);
      a.y = pack2(v0.z, v0.w);
      a.z = pack2(v1.x, v1.y);
      a.w = pack2(v1.z, v1.w);
      bq.x = pack2(v2.x, v2.y);
      bq.y = pack2(v2.z, v2.w);
      bq.z = pack2(v3.x, v3.y);
      bq.w = pack2(v3.z, v3.w);
      unsigned short* d = wtile + wrow * kWBStride + wcol;
      *(uint4*)d = a;
      *(uint4*)(d + 8) = bq;
    }
    __syncthreads();  // wtile ready
#pragma unroll
    for (int sub = 0; sub < 2; ++sub) {
      const int c = cc * 32 + sub * 16 + lrow;
      const float bias = bout[c];
      f32x4 y0 = {bias, bias, bias, bias};
      f32x4 y1 = {bias, bias, bias, bias};
      const unsigned short* wrow_p = wtile + (sub * 16 + lrow) * kWBStride;
#pragma unroll
      for (int ks = 0; ks < 8; ++ks) {
        const bf16x8 wf = *(const bf16x8*)(wrow_p + ks * 32 + quad * 8);
        y0 = __builtin_amdgcn_mfma_f32_16x16x32_bf16(ao[0][ks], wf, y0, 0, 0, 0);
        y1 = __builtin_amdgcn_mfma_f32_16x16x32_bf16(ao[1][ks], wf, y1, 0, 0, 0);
      }
#pragma unroll
      for (int r = 0; r < 4; ++r) {
        const int t = quad * 4 + r;
        const int L = (t * 32 + sub * 16 + lrow) * 17 + wave * 2;
        fbuf[L] = y0[r];
        fbuf[L + 1] = y1[r];
      }
    }
    __syncthreads();
    {
      const int t = tid >> 5, cl = tid & 31;
      float v[16];
#pragma unroll
      for (int i = 0; i < 16; ++i) v[i] = fbuf[tid * 17 + i];
      float* dst = ob + ((size_t)(t * 256 + cc * 32 + cl)) * 1024 + hw0;
#pragma unroll
      for (int u = 0; u < 4; ++u) {
        float4 q;
        q.x = v[u * 4]; q.y = v[u * 4 + 1]; q.z = v[u * 4 + 2]; q.w = v[u * 4 + 3];
        *(float4*)(dst + u * 4) = q;
      }
    }
    __syncthreads();  // fbuf+wtile free for next cc
  }
}

}  // namespace

extern "C" void kernel_launch(void* const* d_in, const int* in_sizes, int n_in,
                              void* d_out, int out_size, void* d_ws, size_t ws_size,
                              hipStream_t stream) {
  const float* x = (const float*)d_in[0];
  const float* rel = (const float*)d_in[1];
  const float* wqkv = (const float*)d_in[2];
  const float* bqkv = (const float*)d_in[3];
  const float* wout = (const float*)d_in[4];
  const float* bout = (const float*)d_in[5];
  float* out = (float*)d_out;
  (void)in_sizes; (void)n_in; (void)out_size; (void)d_ws; (void)ws_size;

  attn_fused<<<256, 512, 0, stream>>>(x, rel, wqkv, bqkv, wout, bout, out);
}